// Round 9
// baseline (220.563 us; speedup 1.0000x reference)
//
#include <hip/hip_runtime.h>
#include <hip/hip_bf16.h>

#define N_TOK 16384
#define C_DIM 256
#define E_NUM 8
#define H_DIM 682
#define H_PAD 768          // 6 * 128 (pad rows/cols are exact zeros)
#define NROWS (N_TOK * 2)  // total expert-assignments (top-2)
#define HB 64              // histogram/scatter blocks
#define APB (NROWS / HB)   // assignments per block = 512

typedef short short8 __attribute__((ext_vector_type(8)));
typedef float floatx4 __attribute__((ext_vector_type(4)));
typedef unsigned int uint;

__device__ inline unsigned short f2bf(float v) {
    union { float f; uint u; } x; x.f = v;
    uint r = (x.u + 0x7fffu + ((x.u >> 16) & 1u)) >> 16;
    return (unsigned short)r;
}
__device__ inline float bf2f(unsigned short v) {
    union { uint u; float f; } x; x.u = ((uint)v) << 16; return x.f;
}

// Async global->LDS 16B/lane. LDS dst: wave-uniform base + lane*16.
__device__ __forceinline__ void load_lds16(const void* g, void* l) {
    __builtin_amdgcn_global_load_lds(
        (const __attribute__((address_space(1))) unsigned int*)g,
        (__attribute__((address_space(3))) unsigned int*)l, 16, 0, 0);
}

// Fused weight convert: w1,w3 [E][682][256] -> [E][768][256] bf16 (zero pad rows);
// w2 [E][256][682] -> [E][256][768] bf16 (zero pad cols). Pair-granular (uint writes).
#define P13 (E_NUM * H_PAD * (C_DIM / 2))
#define P2  (E_NUM * C_DIM * (H_PAD / 2))
__global__ void wconvert(const float* __restrict__ w1, const float* __restrict__ w3,
                         const float* __restrict__ w2, unsigned short* __restrict__ w1b,
                         unsigned short* __restrict__ w3b, unsigned short* __restrict__ w2b) {
    int idx = blockIdx.x * 256 + threadIdx.x;
    if (idx < 2 * P13) {
        const float* src = (idx < P13) ? w1 : w3;
        unsigned short* dst = (idx < P13) ? w1b : w3b;
        int i = (idx < P13) ? idx : idx - P13;
        int e = i / (H_PAD * (C_DIM / 2));
        int rem = i - e * (H_PAD * (C_DIM / 2));
        int r = rem / (C_DIM / 2);
        int c2 = rem - r * (C_DIM / 2);
        uint v = 0;
        if (r < H_DIM) {
            const float2 f = *(const float2*)(src + ((size_t)e * H_DIM + r) * C_DIM + c2 * 2);
            v = (uint)f2bf(f.x) | ((uint)f2bf(f.y) << 16);
        }
        ((uint*)dst)[i] = v;
    } else if (idx < 2 * P13 + P2) {
        int i = idx - 2 * P13;
        int e = i / (C_DIM * (H_PAD / 2));
        int rem = i - e * (C_DIM * (H_PAD / 2));
        int r = rem / (H_PAD / 2);
        int c2 = rem - r * (H_PAD / 2);
        uint v = 0;
        if (c2 * 2 < H_DIM) {  // H_DIM even -> clean pair boundary
            const float2 f = *(const float2*)(w2 + ((size_t)e * C_DIM + r) * H_DIM + c2 * 2);
            v = (uint)f2bf(f.x) | ((uint)f2bf(f.y) << 16);
        }
        ((uint*)w2b)[i] = v;
    }
}

// fp32 router (one wave/token): logits -> softmax -> top2 -> renorm gates.
// Also emits xb = bf16(x) (fused convert; x is already being read here).
__global__ __launch_bounds__(256) void router_kernel(
    const float* __restrict__ x, const float* __restrict__ rw,
    unsigned short* __restrict__ xb, int* __restrict__ as_e, float* __restrict__ as_gate) {
    __shared__ float rws[E_NUM * C_DIM];
    int tid = threadIdx.x;
    for (int i = tid; i < E_NUM * C_DIM; i += 256) rws[i] = rw[i];
    __syncthreads();
    int wave = tid >> 6, lane = tid & 63;
    int t = blockIdx.x * 4 + wave;
    const float4 xv = *(const float4*)(x + (size_t)t * C_DIM + lane * 4);
    uint2 pk;
    pk.x = (uint)f2bf(xv.x) | ((uint)f2bf(xv.y) << 16);
    pk.y = (uint)f2bf(xv.z) | ((uint)f2bf(xv.w) << 16);
    *(uint2*)(xb + (size_t)t * C_DIM + lane * 4) = pk;
    float p[E_NUM];
#pragma unroll
    for (int e = 0; e < E_NUM; e++) {
        const float* wr = &rws[e * C_DIM + lane * 4];
        p[e] = xv.x * wr[0] + xv.y * wr[1] + xv.z * wr[2] + xv.w * wr[3];
    }
#pragma unroll
    for (int off = 32; off >= 1; off >>= 1) {
#pragma unroll
        for (int e = 0; e < E_NUM; e++) p[e] += __shfl_down(p[e], off, 64);
    }
    if (lane == 0) {
        float m = p[0];
#pragma unroll
        for (int e = 1; e < E_NUM; e++) m = fmaxf(m, p[e]);
        float s = 0.f, q[E_NUM];
#pragma unroll
        for (int e = 0; e < E_NUM; e++) { q[e] = expf(p[e] - m); s += q[e]; }
#pragma unroll
        for (int e = 0; e < E_NUM; e++) q[e] /= s;
        int e0 = 0;
#pragma unroll
        for (int e = 1; e < E_NUM; e++) if (q[e] > q[e0]) e0 = e;
        int e1 = (e0 == 0) ? 1 : 0;
#pragma unroll
        for (int e = 0; e < E_NUM; e++) {
            if (e != e0 && q[e] > q[e1]) e1 = e;
        }
        float g0 = q[e0], g1 = q[e1];
        float denom = g0 + g1 + 1e-9f;
        g0 /= denom; g1 /= denom;
        as_e[t * 2] = e0; as_gate[t * 2] = g0;
        as_e[t * 2 + 1] = e1; as_gate[t * 2 + 1] = g1;
    }
}

// Per-block expert histogram (LDS atomics), 64 blocks x 512 assignments.
__global__ __launch_bounds__(256) void hist_kernel(const int* __restrict__ as_e,
                                                   int* __restrict__ block_hist) {
    __shared__ int lh[E_NUM];
    int b = blockIdx.x, tid = threadIdx.x;
    if (tid < E_NUM) lh[tid] = 0;
    __syncthreads();
    for (int i = tid; i < APB; i += 256) atomicAdd(&lh[as_e[b * APB + i]], 1);
    __syncthreads();
    if (tid < E_NUM) block_hist[b * E_NUM + tid] = lh[tid];
}

// Scan: expert totals -> offsets[9]; per-(block,expert) base cursors.
__global__ void scan2_kernel(const int* __restrict__ block_hist, int* __restrict__ offsets,
                             int* __restrict__ block_base) {
    __shared__ int tot[E_NUM], off[E_NUM];
    int e = threadIdx.x;
    if (e < E_NUM) {
        int s = 0;
        for (int b = 0; b < HB; b++) s += block_hist[b * E_NUM + e];
        tot[e] = s;
    }
    __syncthreads();
    if (e == 0) {
        int acc = 0;
        for (int i = 0; i < E_NUM; i++) { off[i] = acc; offsets[i] = acc; acc += tot[i]; }
        offsets[E_NUM] = acc;
    }
    __syncthreads();
    if (e < E_NUM) {
        int acc = off[e];
        for (int b = 0; b < HB; b++) { block_base[b * E_NUM + e] = acc; acc += block_hist[b * E_NUM + e]; }
    }
}

// Scatter: row_token (expert-sorted) + inverse map as_row[a] = row.
__global__ __launch_bounds__(256) void scatter_kernel(
    const int* __restrict__ as_e, const int* __restrict__ block_base,
    int* __restrict__ row_token, int* __restrict__ as_row) {
    __shared__ int cur[E_NUM];
    int b = blockIdx.x, tid = threadIdx.x;
    if (tid < E_NUM) cur[tid] = block_base[b * E_NUM + tid];
    __syncthreads();
    for (int i = tid; i < APB; i += 256) {
        int a = b * APB + i;
        int e = as_e[a];
        int p = atomicAdd(&cur[e], 1);
        row_token[p] = a >> 1;
        as_row[a] = p;
    }
}

// ---------------- Pass 1: h = silu(x.w1^T) * (x.w3^T) ----------------
// Block: 128 rows x 128-col chunk (grid.y = 6). 4 waves = (row-half x matrix);
// each wave computes 64x128 of ONE matrix (w1 or w3): acc[4][8].
// Staging 24 KB/kt covers 2.1 MFLOP (85 FLOP/B). Double-buffered.
__global__ __launch_bounds__(256, 2) void expert_ffn1(
    const unsigned short* __restrict__ xb, const unsigned short* __restrict__ w1b,
    const unsigned short* __restrict__ w3b, const int* __restrict__ offsets,
    const int* __restrict__ row_token, unsigned short* __restrict__ h) {
    int e = blockIdx.x >> 6;
    int mt = blockIdx.x & 63;
    int c = blockIdx.y;  // 0..5
    int off0 = offsets[e], off1 = offsets[e + 1];
    int row0 = off0 + mt * 128;
    if (row0 >= off1) return;
    int mval = min(128, off1 - row0);

    // Per stage: A(128x32)=4096 B1=4096 B3=4096 shorts -> 24 KB; x2 = 48 KB.
    __shared__ union {
        unsigned short buf[2][12288];
        unsigned short Hs[128 * 136];  // 34816 B (overlaps both buffers)
    } sm;

    int tid = threadIdx.x, lane = tid & 63, w = tid >> 6;
    int wrow = w & 1;   // row half
    int wmat = w >> 1;  // 0 -> w1, 1 -> w3
    int ra = tid >> 2;             // staging row (round 0); +64 for round 1
    int acol = (tid & 3) * 8;      // 16B chunk within 32-col k-tile
    int tok0 = row_token[row0 + min(ra, mval - 1)];
    int tok1 = row_token[row0 + min(ra + 64, mval - 1)];
    const unsigned short* a0p = xb + (size_t)tok0 * C_DIM + acol;
    const unsigned short* a1p = xb + (size_t)tok1 * C_DIM + acol;
    const unsigned short* b1p0 = w1b + ((size_t)e * H_PAD + c * 128 + ra) * C_DIM + acol;
    const unsigned short* b1p1 = b1p0 + (size_t)64 * C_DIM;
    const unsigned short* b3p0 = w3b + ((size_t)e * H_PAD + c * 128 + ra) * C_DIM + acol;
    const unsigned short* b3p1 = b3p0 + (size_t)64 * C_DIM;

    int wofs = w * 512;
    auto stage = [&](int kt, int s) {
        int kb = kt * 32;
        unsigned short* base = sm.buf[s];
        load_lds16(a0p + kb, base + wofs);
        load_lds16(a1p + kb, base + 2048 + wofs);
        load_lds16(b1p0 + kb, base + 4096 + wofs);
        load_lds16(b1p1 + kb, base + 6144 + wofs);
        load_lds16(b3p0 + kb, base + 8192 + wofs);
        load_lds16(b3p1 + kb, base + 10240 + wofs);
    };

    int ko = (lane >> 4) * 8;
    int l15 = lane & 15;
    int arowf = wrow * 64 + l15;
    int bbase = wmat ? 8192 : 4096;  // B3 : B1 region within stage buffer
    int quad = lane >> 4;

    stage(0, 0);  // in flight during acc init

    floatx4 acc[4][8];
#pragma unroll
    for (int m = 0; m < 4; m++)
#pragma unroll
        for (int n = 0; n < 8; n++) acc[m][n] = (floatx4){0.f, 0.f, 0.f, 0.f};

    for (int kt = 0; kt < 8; kt++) {
        __syncthreads();
        if (kt + 1 < 8) stage(kt + 1, (kt + 1) & 1);
        const unsigned short* cur = sm.buf[kt & 1];
        short8 af[4], bf[8];
#pragma unroll
        for (int m = 0; m < 4; m++) af[m] = *(short8*)&cur[(arowf + m * 16) * 32 + ko];
#pragma unroll
        for (int n = 0; n < 8; n++) bf[n] = *(short8*)&cur[bbase + (n * 16 + l15) * 32 + ko];
#pragma unroll
        for (int m = 0; m < 4; m++)
#pragma unroll
            for (int n = 0; n < 8; n++)
                acc[m][n] = __builtin_amdgcn_mfma_f32_16x16x32_bf16(af[m], bf[n], acc[m][n], 0, 0, 0);
    }
    __syncthreads();  // all compute done before Hs overwrites buffers

    // Epilogue: w3-waves park h3 in Hs (bf16); w1-waves then apply silu*h3.
    if (wmat == 1) {
#pragma unroll
        for (int m = 0; m < 4; m++)
#pragma unroll
            for (int n = 0; n < 8; n++)
#pragma unroll
                for (int r = 0; r < 4; r++)
                    sm.Hs[(wrow * 64 + m * 16 + quad * 4 + r) * 136 + n * 16 + l15] =
                        f2bf(acc[m][n][r]);
    }
    __syncthreads();
    if (wmat == 0) {
#pragma unroll
        for (int m = 0; m < 4; m++)
#pragma unroll
            for (int n = 0; n < 8; n++)
#pragma unroll
                for (int r = 0; r < 4; r++) {
                    int idx = (wrow * 64 + m * 16 + quad * 4 + r) * 136 + n * 16 + l15;
                    float h1 = acc[m][n][r];
                    float h3 = bf2f(sm.Hs[idx]);
                    float sv = h1 / (1.0f + __expf(-h1)) * h3;
                    sm.Hs[idx] = f2bf(sv);
                }
    }
    __syncthreads();
#pragma unroll
    for (int it = 0; it < 8; it++) {
        int s = it * 256 + tid;
        int row = s >> 4, c16 = s & 15;
        if (row < mval)
            *(int4*)(h + (size_t)(row0 + row) * H_PAD + c * 128 + c16 * 8) =
                *(int4*)&sm.Hs[row * 136 + c16 * 8];
    }
}

// ---------------- Pass 2: y = h . w2^T (bf16 y, no atomics) ----------------
// Block: 128 rows x FULL C=256 (grid = E*64). 4 waves = (row-half x col-half);
// each wave 64x128: acc[4][8]. K = 768, staging 24 KB/kt (85 FLOP/B). Dbuf.
__global__ __launch_bounds__(256, 2) void expert_ffn2(
    const unsigned short* __restrict__ h, const unsigned short* __restrict__ w2b,
    const int* __restrict__ offsets, unsigned short* __restrict__ y) {
    int e = blockIdx.x >> 6;
    int mt = blockIdx.x & 63;
    int off0 = offsets[e], off1 = offsets[e + 1];
    int row0 = off0 + mt * 128;
    if (row0 >= off1) return;
    int mval = min(128, off1 - row0);

    // Per stage: A(128x32)=4096 + B(256x32)=8192 shorts -> 24 KB; x2 = 48 KB.
    __shared__ union {
        unsigned short buf[2][12288];
        unsigned short Hs[128 * 136];
    } sm;

    int tid = threadIdx.x, lane = tid & 63, w = tid >> 6;
    int wrow = w & 1;   // row half
    int wcol = w >> 1;  // col half (of 256)
    int ra = tid >> 2;
    int acol = (tid & 3) * 8;
    const unsigned short* ap0 = h + (size_t)(row0 + ra) * H_PAD + acol;
    const unsigned short* ap1 = ap0 + (size_t)64 * H_PAD;
    const unsigned short* bp = w2b + ((size_t)e * C_DIM + ra) * H_PAD + acol;

    int wofs = w * 512;
    auto stage = [&](int kt, int s) {
        int kb = kt * 32;
        unsigned short* base = sm.buf[s];
        load_lds16(ap0 + kb, base + wofs);
        load_lds16(ap1 + kb, base + 2048 + wofs);
#pragma unroll
        for (int r = 0; r < 4; r++)
            load_lds16(bp + (size_t)r * 64 * H_PAD + kb, base + 4096 + r * 2048 + wofs);
    };

    int ko = (lane >> 4) * 8;
    int l15 = lane & 15;
    int arowf = wrow * 64 + l15;
    int bcolf = wcol * 128;
    int quad = lane >> 4;

    stage(0, 0);

    floatx4 acc[4][8];
#pragma unroll
    for (int m = 0; m < 4; m++)
#pragma unroll
        for (int n = 0; n < 8; n++) acc[m][n] = (floatx4){0.f, 0.f, 0.f, 0.f};

    for (int kt = 0; kt < H_PAD / 32; kt++) {  // 24
        __syncthreads();
        if (kt + 1 < H_PAD / 32) stage(kt + 1, (kt + 1) & 1);
        const unsigned short* cur = sm.buf[kt & 1];
        short8 af[4], bf[8];
#pragma unroll
        for (int m = 0; m < 4; m++) af[m] = *(short8*)&cur[(arowf + m * 16) * 32 + ko];
#pragma unroll
        for (int n = 0; n < 8; n++)
            bf[n] = *(short8*)&cur[4096 + (bcolf + n * 16 + l15) * 32 + ko];
#pragma unroll
        for (int m = 0; m < 4; m++)
#pragma unroll
            for (int n = 0; n < 8; n++)
                acc[m][n] = __builtin_amdgcn_mfma_f32_16x16x32_bf16(af[m], bf[n], acc[m][n], 0, 0, 0);
    }
    __syncthreads();

    // Epilogue: two 128-col passes through Hs
#pragma unroll
    for (int p = 0; p < 2; p++) {
        if (wcol == p) {
#pragma unroll
            for (int m = 0; m < 4; m++)
#pragma unroll
                for (int n = 0; n < 8; n++)
#pragma unroll
                    for (int r = 0; r < 4; r++)
                        sm.Hs[(wrow * 64 + m * 16 + quad * 4 + r) * 136 + n * 16 + l15] =
                            f2bf(acc[m][n][r]);
        }
        __syncthreads();
#pragma unroll
        for (int it = 0; it < 8; it++) {
            int s = it * 256 + tid;
            int row = s >> 4, c16 = s & 15;
            if (row < mval)
                *(int4*)(y + (size_t)(row0 + row) * C_DIM + p * 128 + c16 * 8) =
                    *(int4*)&sm.Hs[row * 136 + c16 * 8];
        }
        __syncthreads();
    }
}

// Combine: out[t][:] = g0*y[row(2t)][:] + g1*y[row(2t+1)][:]  (fp32 out)
__global__ __launch_bounds__(256) void combine_kernel(
    const unsigned short* __restrict__ y, const int* __restrict__ as_row,
    const float* __restrict__ as_gate, float* __restrict__ out) {
    int tid = threadIdx.x, lane = tid & 63;
    int t = blockIdx.x * 4 + (tid >> 6);
    int r0 = as_row[2 * t], r1 = as_row[2 * t + 1];
    float g0 = as_gate[2 * t], g1 = as_gate[2 * t + 1];
    uint2 a = *(const uint2*)(y + (size_t)r0 * C_DIM + lane * 4);
    uint2 b = *(const uint2*)(y + (size_t)r1 * C_DIM + lane * 4);
    float4 o;
    o.x = g0 * bf2f((unsigned short)(a.x & 0xffff)) + g1 * bf2f((unsigned short)(b.x & 0xffff));
    o.y = g0 * bf2f((unsigned short)(a.x >> 16)) + g1 * bf2f((unsigned short)(b.x >> 16));
    o.z = g0 * bf2f((unsigned short)(a.y & 0xffff)) + g1 * bf2f((unsigned short)(b.y & 0xffff));
    o.w = g0 * bf2f((unsigned short)(a.y >> 16)) + g1 * bf2f((unsigned short)(b.y >> 16));
    *(float4*)(out + (size_t)t * C_DIM + lane * 4) = o;
}

extern "C" void kernel_launch(void* const* d_in, const int* in_sizes, int n_in,
                              void* d_out, int out_size, void* d_ws, size_t ws_size,
                              hipStream_t stream) {
    const float* x = (const float*)d_in[0];
    const float* rw = (const float*)d_in[1];
    const float* w1 = (const float*)d_in[2];
    const float* w2 = (const float*)d_in[3];
    const float* w3 = (const float*)d_in[4];
    float* out = (float*)d_out;

    char* ws = (char*)d_ws;
    size_t o = 0;
    auto alloc = [&](size_t bytes) {
        void* p = ws + o;
        o = (o + bytes + 255) & ~(size_t)255;
        return p;
    };
    unsigned short* xb = (unsigned short*)alloc((size_t)N_TOK * C_DIM * 2);
    unsigned short* w1b = (unsigned short*)alloc((size_t)E_NUM * H_PAD * C_DIM * 2);
    unsigned short* w3b = (unsigned short*)alloc((size_t)E_NUM * H_PAD * C_DIM * 2);
    unsigned short* w2b = (unsigned short*)alloc((size_t)E_NUM * C_DIM * H_PAD * 2);
    unsigned short* hbuf = (unsigned short*)alloc((size_t)(NROWS + 128) * H_PAD * 2);
    unsigned short* ybuf = (unsigned short*)alloc((size_t)NROWS * C_DIM * 2);
    int* offsets = (int*)alloc((E_NUM + 1) * 4);
    int* as_e = (int*)alloc(NROWS * 4);
    float* as_gate = (float*)alloc(NROWS * 4);
    int* row_token = (int*)alloc(NROWS * 4);
    int* as_row = (int*)alloc(NROWS * 4);
    int* block_hist = (int*)alloc(HB * E_NUM * 4);
    int* block_base = (int*)alloc(HB * E_NUM * 4);

    wconvert<<<(2 * P13 + P2 + 255) / 256, 256, 0, stream>>>(w1, w3, w2, w1b, w3b, w2b);
    router_kernel<<<N_TOK / 4, 256, 0, stream>>>(x, rw, xb, as_e, as_gate);
    hist_kernel<<<HB, 256, 0, stream>>>(as_e, block_hist);
    scan2_kernel<<<1, 64, 0, stream>>>(block_hist, offsets, block_base);
    scatter_kernel<<<HB, 256, 0, stream>>>(as_e, block_base, row_token, as_row);

    expert_ffn1<<<dim3(E_NUM * 64, 6), 256, 0, stream>>>(xb, w1b, w3b, offsets, row_token, hbuf);
    expert_ffn2<<<E_NUM * 64, 256, 0, stream>>>(hbuf, w2b, offsets, ybuf);
    combine_kernel<<<N_TOK / 4, 256, 0, stream>>>(ybuf, as_row, as_gate, out);
}

// Round 12
// 200.923 us; speedup vs baseline: 1.0977x; 1.0977x over previous
//
#include <hip/hip_runtime.h>
#include <hip/hip_bf16.h>

#define N_TOK 16384
#define C_DIM 256
#define E_NUM 8
#define H_DIM 682
#define H_PAD 768          // 6 * 128 (pad rows/cols are exact zeros)
#define NROWS (N_TOK * 2)  // total expert-assignments (top-2)
#define HB 64              // histogram/scatter blocks
#define APB (NROWS / HB)   // assignments per block = 512

typedef short short8 __attribute__((ext_vector_type(8)));
typedef float floatx4 __attribute__((ext_vector_type(4)));
typedef unsigned int uint;

__device__ inline unsigned short f2bf(float v) {
    union { float f; uint u; } x; x.f = v;
    uint r = (x.u + 0x7fffu + ((x.u >> 16) & 1u)) >> 16;
    return (unsigned short)r;
}
__device__ inline float bf2f(unsigned short v) {
    union { uint u; float f; } x; x.u = ((uint)v) << 16; return x.f;
}

// Async global->LDS 16B/lane. LDS dst: wave-uniform base + lane*16.
__device__ __forceinline__ void load_lds16(const void* g, void* l) {
    __builtin_amdgcn_global_load_lds(
        (const __attribute__((address_space(1))) unsigned int*)g,
        (__attribute__((address_space(3))) unsigned int*)l, 16, 0, 0);
}

// Weight convert: w1,w3 [E][682][256] -> [E][768][256] bf16 row-major (pad rows);
// w2 [E][256][682] -> kt-TILED w2t [e][kt(24)][256 rows][32] bf16 (pad cols).
#define P13 (E_NUM * H_PAD * (C_DIM / 2))   // 786432 uints per matrix
#define W2U (E_NUM * 24 * 4096)             // 786432 uints
__global__ void wconvert(const float* __restrict__ w1, const float* __restrict__ w3,
                         const float* __restrict__ w2, unsigned short* __restrict__ w1b,
                         unsigned short* __restrict__ w3b, unsigned short* __restrict__ w2t) {
    int idx = blockIdx.x * 256 + threadIdx.x;
    if (idx < 2 * P13) {
        const float* src = (idx < P13) ? w1 : w3;
        unsigned short* dst = (idx < P13) ? w1b : w3b;
        int i = (idx < P13) ? idx : idx - P13;
        int e = i / (H_PAD * (C_DIM / 2));
        int rem = i - e * (H_PAD * (C_DIM / 2));
        int r = rem / (C_DIM / 2);
        int c2 = rem - r * (C_DIM / 2);
        uint v = 0;
        if (r < H_DIM) {
            const float2 f = *(const float2*)(src + ((size_t)e * H_DIM + r) * C_DIM + c2 * 2);
            v = (uint)f2bf(f.x) | ((uint)f2bf(f.y) << 16);
        }
        ((uint*)dst)[i] = v;
    } else if (idx < 2 * P13 + W2U) {
        int i = idx - 2 * P13;
        int e = i / 98304;   int r1 = i % 98304;    // 24*4096
        int kt = r1 / 4096;  int r2 = r1 % 4096;
        int row = r2 / 16;   int k2 = r2 % 16;
        int col = kt * 32 + k2 * 2;
        uint v = 0;
        if (col < H_DIM) {   // H_DIM even -> pair never straddles
            const float* s = w2 + (((size_t)e * C_DIM + row) * H_DIM + col);
            v = (uint)f2bf(s[0]) | ((uint)f2bf(s[1]) << 16);
        }
        ((uint*)w2t)[i] = v;
    }
}

// fp32 router (one wave/token): logits -> softmax -> top2 -> renorm gates.
// Also emits xb = bf16(x).
__global__ __launch_bounds__(256) void router_kernel(
    const float* __restrict__ x, const float* __restrict__ rw,
    unsigned short* __restrict__ xb, int* __restrict__ as_e, float* __restrict__ as_gate) {
    __shared__ float rws[E_NUM * C_DIM];
    int tid = threadIdx.x;
    for (int i = tid; i < E_NUM * C_DIM; i += 256) rws[i] = rw[i];
    __syncthreads();
    int wave = tid >> 6, lane = tid & 63;
    int t = blockIdx.x * 4 + wave;
    const float4 xv = *(const float4*)(x + (size_t)t * C_DIM + lane * 4);
    uint2 pk;
    pk.x = (uint)f2bf(xv.x) | ((uint)f2bf(xv.y) << 16);
    pk.y = (uint)f2bf(xv.z) | ((uint)f2bf(xv.w) << 16);
    *(uint2*)(xb + (size_t)t * C_DIM + lane * 4) = pk;
    float p[E_NUM];
#pragma unroll
    for (int e = 0; e < E_NUM; e++) {
        const float* wr = &rws[e * C_DIM + lane * 4];
        p[e] = xv.x * wr[0] + xv.y * wr[1] + xv.z * wr[2] + xv.w * wr[3];
    }
#pragma unroll
    for (int off = 32; off >= 1; off >>= 1) {
#pragma unroll
        for (int e = 0; e < E_NUM; e++) p[e] += __shfl_down(p[e], off, 64);
    }
    if (lane == 0) {
        float m = p[0];
#pragma unroll
        for (int e = 1; e < E_NUM; e++) m = fmaxf(m, p[e]);
        float s = 0.f, q[E_NUM];
#pragma unroll
        for (int e = 0; e < E_NUM; e++) { q[e] = expf(p[e] - m); s += q[e]; }
#pragma unroll
        for (int e = 0; e < E_NUM; e++) q[e] /= s;
        int e0 = 0;
#pragma unroll
        for (int e = 1; e < E_NUM; e++) if (q[e] > q[e0]) e0 = e;
        int e1 = (e0 == 0) ? 1 : 0;
#pragma unroll
        for (int e = 0; e < E_NUM; e++) {
            if (e != e0 && q[e] > q[e1]) e1 = e;
        }
        float g0 = q[e0], g1 = q[e1];
        float denom = g0 + g1 + 1e-9f;
        g0 /= denom; g1 /= denom;
        as_e[t * 2] = e0; as_gate[t * 2] = g0;
        as_e[t * 2 + 1] = e1; as_gate[t * 2 + 1] = g1;
    }
}

// Per-block expert histogram (LDS atomics), 64 blocks x 512 assignments.
__global__ __launch_bounds__(256) void hist_kernel(const int* __restrict__ as_e,
                                                   int* __restrict__ block_hist) {
    __shared__ int lh[E_NUM];
    int b = blockIdx.x, tid = threadIdx.x;
    if (tid < E_NUM) lh[tid] = 0;
    __syncthreads();
    for (int i = tid; i < APB; i += 256) atomicAdd(&lh[as_e[b * APB + i]], 1);
    __syncthreads();
    if (tid < E_NUM) block_hist[b * E_NUM + tid] = lh[tid];
}

// Scan: expert totals -> offsets[9]; per-(block,expert) base cursors.
__global__ void scan2_kernel(const int* __restrict__ block_hist, int* __restrict__ offsets,
                             int* __restrict__ block_base) {
    __shared__ int tot[E_NUM], off[E_NUM];
    int e = threadIdx.x;
    if (e < E_NUM) {
        int s = 0;
        for (int b = 0; b < HB; b++) s += block_hist[b * E_NUM + e];
        tot[e] = s;
    }
    __syncthreads();
    if (e == 0) {
        int acc = 0;
        for (int i = 0; i < E_NUM; i++) { off[i] = acc; offsets[i] = acc; acc += tot[i]; }
        offsets[E_NUM] = acc;
    }
    __syncthreads();
    if (e < E_NUM) {
        int acc = off[e];
        for (int b = 0; b < HB; b++) { block_base[b * E_NUM + e] = acc; acc += block_hist[b * E_NUM + e]; }
    }
}

// Scatter: row_token (expert-sorted) + inverse map as_row[a] = row.
__global__ __launch_bounds__(256) void scatter_kernel(
    const int* __restrict__ as_e, const int* __restrict__ block_base,
    int* __restrict__ row_token, int* __restrict__ as_row) {
    __shared__ int cur[E_NUM];
    int b = blockIdx.x, tid = threadIdx.x;
    if (tid < E_NUM) cur[tid] = block_base[b * E_NUM + tid];
    __syncthreads();
    for (int i = tid; i < APB; i += 256) {
        int a = b * APB + i;
        int e = as_e[a];
        int p = atomicAdd(&cur[e], 1);
        row_token[p] = a >> 1;
        as_row[a] = p;
    }
}

// ---------------- Pass 1: h = silu(x.w1^T) * (x.w3^T) ----------------
// Round-8 structure, byte-identical: 128 rows x 128-col chunk (grid.y=6);
// 2x2 waves, each 64x64 of BOTH matrices. Double-buffered LDS staging.
__global__ __launch_bounds__(256, 2) void expert_ffn1(
    const unsigned short* __restrict__ xb, const unsigned short* __restrict__ w1b,
    const unsigned short* __restrict__ w3b, const int* __restrict__ offsets,
    const int* __restrict__ row_token, unsigned short* __restrict__ h) {
    int e = blockIdx.x >> 6;
    int mt = blockIdx.x & 63;
    int c = blockIdx.y;  // 0..5
    int off0 = offsets[e], off1 = offsets[e + 1];
    int row0 = off0 + mt * 128;
    if (row0 >= off1) return;
    int mval = min(128, off1 - row0);

    // Per stage: A(128x32)=4096 B1=4096 B3=4096 shorts -> 24 KB; x2 = 48 KB.
    __shared__ union {
        unsigned short buf[2][12288];
        unsigned short Hs[128 * 136];  // 34816 B (overlaps both buffers)
    } sm;

    int tid = threadIdx.x, lane = tid & 63, w = tid >> 6;
    int wm = w & 1, wn = w >> 1;
    int ra = tid >> 2;             // staging row (round 0); +64 for round 1
    int acol = (tid & 3) * 8;      // 16B chunk within 32-col k-tile
    int tok0 = row_token[row0 + min(ra, mval - 1)];
    int tok1 = row_token[row0 + min(ra + 64, mval - 1)];
    const unsigned short* a0p = xb + (size_t)tok0 * C_DIM + acol;
    const unsigned short* a1p = xb + (size_t)tok1 * C_DIM + acol;
    const unsigned short* b1p0 = w1b + ((size_t)e * H_PAD + c * 128 + ra) * C_DIM + acol;
    const unsigned short* b1p1 = b1p0 + (size_t)64 * C_DIM;
    const unsigned short* b3p0 = w3b + ((size_t)e * H_PAD + c * 128 + ra) * C_DIM + acol;
    const unsigned short* b3p1 = b3p0 + (size_t)64 * C_DIM;

    int wofs = w * 512;
    auto stage = [&](int kt, int s) {
        int kb = kt * 32;
        unsigned short* base = sm.buf[s];
        load_lds16(a0p + kb, base + wofs);
        load_lds16(a1p + kb, base + 2048 + wofs);
        load_lds16(b1p0 + kb, base + 4096 + wofs);
        load_lds16(b1p1 + kb, base + 6144 + wofs);
        load_lds16(b3p0 + kb, base + 8192 + wofs);
        load_lds16(b3p1 + kb, base + 10240 + wofs);
    };

    int ko = (lane >> 4) * 8;
    int l15 = lane & 15;
    int arowf = wm * 64 + l15;
    int browf = wn * 64 + l15;
    int quad = lane >> 4;

    stage(0, 0);  // in flight during acc init

    floatx4 acc1[4][4], acc3[4][4];
#pragma unroll
    for (int m = 0; m < 4; m++)
#pragma unroll
        for (int n = 0; n < 4; n++) {
            acc1[m][n] = (floatx4){0.f, 0.f, 0.f, 0.f};
            acc3[m][n] = (floatx4){0.f, 0.f, 0.f, 0.f};
        }

    for (int kt = 0; kt < 8; kt++) {
        __syncthreads();           // drains stage(kt); all waves done reading other buf
        if (kt + 1 < 8) stage(kt + 1, (kt + 1) & 1);  // in flight during compute(kt)
        const unsigned short* cur = sm.buf[kt & 1];
        short8 af[4], b1f[4], b3f[4];
#pragma unroll
        for (int m = 0; m < 4; m++) af[m] = *(short8*)&cur[(arowf + m * 16) * 32 + ko];
#pragma unroll
        for (int n = 0; n < 4; n++) {
            b1f[n] = *(short8*)&cur[4096 + (browf + n * 16) * 32 + ko];
            b3f[n] = *(short8*)&cur[8192 + (browf + n * 16) * 32 + ko];
        }
#pragma unroll
        for (int m = 0; m < 4; m++)
#pragma unroll
            for (int n = 0; n < 4; n++) {
                acc1[m][n] = __builtin_amdgcn_mfma_f32_16x16x32_bf16(af[m], b1f[n], acc1[m][n], 0, 0, 0);
                acc3[m][n] = __builtin_amdgcn_mfma_f32_16x16x32_bf16(af[m], b3f[n], acc3[m][n], 0, 0, 0);
            }
    }
    __syncthreads();  // all compute done before Hs overwrites buffers

    // Epilogue: silu(h1)*h3 -> Hs (bf16) -> coalesced 16B stores
#pragma unroll
    for (int m = 0; m < 4; m++)
#pragma unroll
        for (int n = 0; n < 4; n++)
#pragma unroll
            for (int r = 0; r < 4; r++) {
                float h1 = acc1[m][n][r], h3 = acc3[m][n][r];
                float sv = h1 / (1.0f + __expf(-h1)) * h3;
                sm.Hs[(wm * 64 + m * 16 + quad * 4 + r) * 136 + wn * 64 + n * 16 + l15] = f2bf(sv);
            }
    __syncthreads();
#pragma unroll
    for (int it = 0; it < 8; it++) {
        int s = it * 256 + tid;
        int row = s >> 4, c16 = s & 15;
        if (row < mval)
            *(int4*)(h + (size_t)(row0 + row) * H_PAD + c * 128 + c16 * 8) =
                *(int4*)&sm.Hs[row * 136 + c16 * 8];
    }
}

// ---------------- Pass 2: y = h . w2^T (bf16 y, no atomics) ----------------
// Round-8 structure; ONLY change: B staged from kt-tiled w2t (contiguous bursts).
__global__ __launch_bounds__(256, 2) void expert_ffn2(
    const unsigned short* __restrict__ h, const unsigned short* __restrict__ w2t,
    const int* __restrict__ offsets, unsigned short* __restrict__ y) {
    int e = blockIdx.x >> 6;
    int mt = blockIdx.x & 63;
    int p = blockIdx.y;  // 0..1 (C chunk)
    int off0 = offsets[e], off1 = offsets[e + 1];
    int row0 = off0 + mt * 128;
    if (row0 >= off1) return;
    int mval = min(128, off1 - row0);

    // Per stage: A(128x32)=4096 B(128x32)=4096 shorts -> 16 KB; x2 = 32 KB.
    __shared__ union {
        unsigned short buf[2][8192];
        unsigned short Hs[128 * 136];  // 34816 B
    } sm;

    int tid = threadIdx.x, lane = tid & 63, w = tid >> 6;
    int wm = w & 1, wn = w >> 1;
    int ra = tid >> 2;
    int acol = (tid & 3) * 8;
    const unsigned short* ap0 = h + (size_t)(row0 + ra) * H_PAD + acol;
    const unsigned short* ap1 = ap0 + (size_t)64 * H_PAD;
    // kt-tiled w2t: [e][kt(24)][256][32]; chunk p = rows p*128.. -> +p*4096 shorts.
    const unsigned short* btp = w2t + (size_t)e * 196608 + (size_t)p * 4096 +
                                w * 1024 + lane * 8;

    int wofs = w * 512;
    int bofs = w * 1024;
    auto stage = [&](int kt, int s) {
        int kb = kt * 32;
        unsigned short* base = sm.buf[s];
        load_lds16(ap0 + kb, base + wofs);
        load_lds16(ap1 + kb, base + 2048 + wofs);
        const unsigned short* bs = btp + kt * 8192;
        load_lds16(bs,       base + 4096 + bofs);
        load_lds16(bs + 512, base + 4096 + bofs + 512);
    };

    int ko = (lane >> 4) * 8;
    int l15 = lane & 15;
    int arowf = wm * 64 + l15;
    int browf = wn * 64 + l15;
    int quad = lane >> 4;

    stage(0, 0);

    floatx4 acc[4][4];
#pragma unroll
    for (int m = 0; m < 4; m++)
#pragma unroll
        for (int n = 0; n < 4; n++) acc[m][n] = (floatx4){0.f, 0.f, 0.f, 0.f};

    for (int kt = 0; kt < H_PAD / 32; kt++) {  // 24
        __syncthreads();
        if (kt + 1 < H_PAD / 32) stage(kt + 1, (kt + 1) & 1);
        const unsigned short* cur = sm.buf[kt & 1];
        short8 af[4], bf[4];
#pragma unroll
        for (int m = 0; m < 4; m++) af[m] = *(short8*)&cur[(arowf + m * 16) * 32 + ko];
#pragma unroll
        for (int n = 0; n < 4; n++) bf[n] = *(short8*)&cur[4096 + (browf + n * 16) * 32 + ko];
#pragma unroll
        for (int m = 0; m < 4; m++)
#pragma unroll
            for (int n = 0; n < 4; n++)
                acc[m][n] = __builtin_amdgcn_mfma_f32_16x16x32_bf16(af[m], bf[n], acc[m][n], 0, 0, 0);
    }
    __syncthreads();

    // Epilogue: y chunk (bf16) via Hs transpose
#pragma unroll
    for (int m = 0; m < 4; m++)
#pragma unroll
        for (int n = 0; n < 4; n++)
#pragma unroll
            for (int r = 0; r < 4; r++)
                sm.Hs[(wm * 64 + m * 16 + quad * 4 + r) * 136 + wn * 64 + n * 16 + l15] =
                    f2bf(acc[m][n][r]);
    __syncthreads();
#pragma unroll
    for (int it = 0; it < 8; it++) {
        int s = it * 256 + tid;
        int row = s >> 4, c16 = s & 15;
        if (row < mval)
            *(int4*)(y + (size_t)(row0 + row) * C_DIM + p * 128 + c16 * 8) =
                *(int4*)&sm.Hs[row * 136 + c16 * 8];
    }
}

// Combine: out[t][:] = g0*y[row(2t)][:] + g1*y[row(2t+1)][:]  (fp32 out)
__global__ __launch_bounds__(256) void combine_kernel(
    const unsigned short* __restrict__ y, const int* __restrict__ as_row,
    const float* __restrict__ as_gate, float* __restrict__ out) {
    int tid = threadIdx.x, lane = tid & 63;
    int t = blockIdx.x * 4 + (tid >> 6);
    int r0 = as_row[2 * t], r1 = as_row[2 * t + 1];
    float g0 = as_gate[2 * t], g1 = as_gate[2 * t + 1];
    uint2 a = *(const uint2*)(y + (size_t)r0 * C_DIM + lane * 4);
    uint2 b = *(const uint2*)(y + (size_t)r1 * C_DIM + lane * 4);
    float4 o;
    o.x = g0 * bf2f((unsigned short)(a.x & 0xffff)) + g1 * bf2f((unsigned short)(b.x & 0xffff));
    o.y = g0 * bf2f((unsigned short)(a.x >> 16)) + g1 * bf2f((unsigned short)(b.x >> 16));
    o.z = g0 * bf2f((unsigned short)(a.y & 0xffff)) + g1 * bf2f((unsigned short)(b.y & 0xffff));
    o.w = g0 * bf2f((unsigned short)(a.y >> 16)) + g1 * bf2f((unsigned short)(b.y >> 16));
    *(float4*)(out + (size_t)t * C_DIM + lane * 4) = o;
}

extern "C" void kernel_launch(void* const* d_in, const int* in_sizes, int n_in,
                              void* d_out, int out_size, void* d_ws, size_t ws_size,
                              hipStream_t stream) {
    const float* x = (const float*)d_in[0];
    const float* rw = (const float*)d_in[1];
    const float* w1 = (const float*)d_in[2];
    const float* w2 = (const float*)d_in[3];
    const float* w3 = (const float*)d_in[4];
    float* out = (float*)d_out;

    char* ws = (char*)d_ws;
    size_t o = 0;
    auto alloc = [&](size_t bytes) {
        void* p = ws + o;
        o = (o + bytes + 255) & ~(size_t)255;
        return p;
    };
    unsigned short* xb = (unsigned short*)alloc((size_t)N_TOK * C_DIM * 2);
    unsigned short* w1b = (unsigned short*)alloc((size_t)E_NUM * H_PAD * C_DIM * 2);
    unsigned short* w3b = (unsigned short*)alloc((size_t)E_NUM * H_PAD * C_DIM * 2);
    unsigned short* w2t = (unsigned short*)alloc((size_t)W2U * 4);
    unsigned short* hbuf = (unsigned short*)alloc((size_t)(NROWS + 128) * H_PAD * 2);
    unsigned short* ybuf = (unsigned short*)alloc((size_t)NROWS * C_DIM * 2);
    int* offsets = (int*)alloc((E_NUM + 1) * 4);
    int* as_e = (int*)alloc(NROWS * 4);
    float* as_gate = (float*)alloc(NROWS * 4);
    int* row_token = (int*)alloc(NROWS * 4);
    int* as_row = (int*)alloc(NROWS * 4);
    int* block_hist = (int*)alloc(HB * E_NUM * 4);
    int* block_base = (int*)alloc(HB * E_NUM * 4);

    wconvert<<<(2 * P13 + W2U + 255) / 256, 256, 0, stream>>>(w1, w3, w2, w1b, w3b, w2t);
    router_kernel<<<N_TOK / 4, 256, 0, stream>>>(x, rw, xb, as_e, as_gate);
    hist_kernel<<<HB, 256, 0, stream>>>(as_e, block_hist);
    scan2_kernel<<<1, 64, 0, stream>>>(block_hist, offsets, block_base);
    scatter_kernel<<<HB, 256, 0, stream>>>(as_e, block_base, row_token, as_row);

    expert_ffn1<<<dim3(E_NUM * 64, 6), 256, 0, stream>>>(xb, w1b, w3b, offsets, row_token, hbuf);
    expert_ffn2<<<dim3(E_NUM * 64, 2), 256, 0, stream>>>(hbuf, w2t, offsets, ybuf);
    combine_kernel<<<N_TOK / 4, 256, 0, stream>>>(ybuf, as_row, as_gate, out);
}